// Round 1
// 163.351 us; speedup vs baseline: 1.0115x; 1.0115x over previous
//
#include <hip/hip_runtime.h>

// Problem constants from the reference
#define BB 32
#define AA 3
#define HH 64
#define WW 64
#define NC 80
#define TT 50
#define THRESH 0.5f

#define NTGT (BB * TT)                      // 1600 targets
#define WAVES_PER_BLOCK 16                  // 1024 threads/block
#define NBLOCKS (NTGT / WAVES_PER_BLOCK)    // 100 blocks

// ws layout: ws[0..99] = per-block sum(ce*mask), ws[100..199] = per-block cnt.
// Slots are fully OVERWRITTEN before being read by the finalize kernel, so the
// harness's 0xAA poison of d_ws needs no memset — the init node is gone, and so
// are all device-scope atomics / tickets / __threadfence L2 writebacks.

__global__ __launch_bounds__(WAVES_PER_BLOCK * 64) void class_loss_partial(
    const float* __restrict__ output,    // (B, A, H, W, 5+NC) f32
    const float* __restrict__ anchors,   // (A, 2) f32
    const float* __restrict__ targets,   // (B, T, 5) f32
    float* __restrict__ ws)              // partial slots (no init required)
{
    __shared__ float s_ce[WAVES_PER_BLOCK];
    __shared__ float s_cnt[WAVES_PER_BLOCK];

    const int wave = threadIdx.x >> 6;
    const int lane = threadIdx.x & 63;
    const int idx  = blockIdx.x * WAVES_PER_BLOCK + wave;   // target 0..1599
    const int b    = idx / TT;
    const int t    = idx - b * TT;

    // Per-target scalars (redundant across the wave; scalar-unit friendly).
    const float* tgt = targets + (size_t)(b * TT + t) * 5;
    const float clsf = tgt[0];
    const float tx   = tgt[1];
    const float ty   = tgt[2];
    const float tw   = tgt[3] * (float)WW;
    const float th   = tgt[4] * (float)HH;

    int t_i = (int)(tx * (float)WW);  t_i = min(max(t_i, 0), WW - 1);
    int t_j = (int)(ty * (float)HH);  t_j = min(max(t_j, 0), HH - 1);

    // Best anchor by IoU (strict > == jnp.argmax first-max semantics)
    float best_iou = -1.0f;
    int   best_a   = 0;
    #pragma unroll
    for (int a = 0; a < AA; ++a) {
        const float aw = anchors[a * 2 + 0];
        const float ah = anchors[a * 2 + 1];
        const float inter = fminf(aw, tw) * fminf(ah, th);
        const float uni   = aw * ah + tw * th - inter;
        const float iou   = inter / uni;
        if (iou > best_iou) { best_iou = iou; best_a = a; }
    }

    float ce = 0.0f, msk = 0.0f;
    if (best_iou > THRESH) {          // wave-uniform branch
        const size_t row_off =
            ((((size_t)b * AA + best_a) * HH + t_j) * WW + t_i) * (size_t)(5 + NC) + 5;
        const float* row = output + row_off;

        const float v0 = row[lane];                              // coalesced 64 floats
        const bool  has2 = (lane < NC - 64);                     // lanes 0..15
        const float v1 = has2 ? row[lane + 64] : -INFINITY;

        float m = fmaxf(v0, v1);
        #pragma unroll
        for (int off = 32; off > 0; off >>= 1)
            m = fmaxf(m, __shfl_xor(m, off, 64));

        float s = expf(v0 - m) + (has2 ? expf(v1 - m) : 0.0f);
        #pragma unroll
        for (int off = 32; off > 0; off >>= 1)
            s += __shfl_xor(s, off, 64);

        if (lane == 0) {
            const int cls = (int)clsf;                           // exact in f32
            const float lc = row[cls];                           // L1-hot
            ce  = -(lc - m - logf(s));
            msk = 1.0f;
        }
    }

    if (lane == 0) { s_ce[wave] = ce; s_cnt[wave] = msk; }
    __syncthreads();

    // Wave 0 reduces the 16 per-wave partials; plain slot store — no atomics,
    // no ticket, no __threadfence. Kernel-boundary release makes the writes
    // visible to the finalize dispatch on the same stream.
    if (wave == 0) {
        float rc = (lane < WAVES_PER_BLOCK) ? s_ce[lane]  : 0.0f;
        float rn = (lane < WAVES_PER_BLOCK) ? s_cnt[lane] : 0.0f;
        #pragma unroll
        for (int off = 8; off > 0; off >>= 1) {   // lanes 0..15 hold data
            rc += __shfl_xor(rc, off, 64);
            rn += __shfl_xor(rn, off, 64);
        }
        if (lane == 0) {
            ws[blockIdx.x]           = rc;
            ws[NBLOCKS + blockIdx.x] = rn;
        }
    }
}

__global__ __launch_bounds__(64) void class_loss_final(
    const float* __restrict__ ws,
    float* __restrict__ out)
{
    const int lane = threadIdx.x;        // single wave
    float rc = 0.0f, rn = 0.0f;
    if (lane < NBLOCKS)      { rc += ws[lane];       rn += ws[NBLOCKS + lane]; }
    if (lane + 64 < NBLOCKS) { rc += ws[lane + 64];  rn += ws[NBLOCKS + lane + 64]; }
    #pragma unroll
    for (int off = 32; off > 0; off >>= 1) {
        rc += __shfl_xor(rc, off, 64);
        rn += __shfl_xor(rn, off, 64);
    }
    if (lane == 0) out[0] = (rn > 0.0f) ? (rc / rn) : 0.0f;
}

extern "C" void kernel_launch(void* const* d_in, const int* in_sizes, int n_in,
                              void* d_out, int out_size, void* d_ws, size_t ws_size,
                              hipStream_t stream) {
    const float* output  = (const float*)d_in[0];   // (32,3,64,64,85)
    const float* anchors = (const float*)d_in[1];   // (3,2)
    const float* targets = (const float*)d_in[2];   // (32,50,5)
    float* ws  = (float*)d_ws;
    float* out = (float*)d_out;

    // No memset: every ws slot consumed is overwritten first.
    class_loss_partial<<<NBLOCKS, WAVES_PER_BLOCK * 64, 0, stream>>>(
        output, anchors, targets, ws);
    class_loss_final<<<1, 64, 0, stream>>>(ws, out);
}